// Round 16
// baseline (502.330 us; speedup 1.0000x reference)
//
#include <hip/hip_runtime.h>
#include <hip/hip_bf16.h>
#include <math.h>

#define P_CHUNK 8192
#define NBKT 1024   // bucket = dst>>7; used buckets = ceil(N/128)
#define CAP  4096   // slab capacity per bucket (max real bucket ~2350)

typedef float f4 __attribute__((ext_vector_type(4)));

__device__ __forceinline__ float lrelu(float x){ return x < 0.f ? 0.2f*x : x; }
__device__ __forceinline__ float elu_(float x){ return x > 0.f ? x : expm1f(x); }

// ---------------- device bodies ----------------

// GEMM(128x128) + attention-logit epilogue. 128-row tile, 256 thr = 16x16,
// thread owns 8x8 (r14 body — best measured non-aggr). xs natural [row][132].
// W direct from global (L2-resident). ONE barrier.
template<int H, bool GATHER>
__device__ __forceinline__ void gemm_body(float (*xs)[132], int bid,
    const float* __restrict__ X, const int* __restrict__ idx,
    const float* __restrict__ W, const float* __restrict__ asrc,
    const float* __restrict__ adst, float* __restrict__ Hout,
    float* __restrict__ als, float* __restrict__ ald, int n)
{
  int tid = threadIdx.x;
  int tr = tid >> 4, tc = tid & 15;
  int r8 = tr*8, c8 = tc*8;
  int row0 = bid * 128;

  #pragma unroll
  for (int j=0;j<16;j++){
    int e = tid + j*256;
    int r = e >> 5, cq = e & 31;
    int gr = row0 + r;
    f4 v = (f4)(0.f);
    if (gr < n){
      int srow = GATHER ? idx[gr] : gr;
      v = *reinterpret_cast<const f4*>(&X[(size_t)srow*128 + cq*4]);
    }
    *reinterpret_cast<f4*>(&xs[r][cq*4]) = v;
  }
  __syncthreads();

  float acc[8][8];
  #pragma unroll
  for (int r=0;r<8;r++)
    #pragma unroll
    for (int i=0;i<8;i++) acc[r][i] = 0.f;

  #pragma unroll 2
  for (int kq=0;kq<32;kq++){
    int k0 = kq*4;
    f4 xv[8], wv0[4], wv1[4];
    #pragma unroll
    for (int i=0;i<8;i++) xv[i] = *reinterpret_cast<const f4*>(&xs[r8+i][k0]);
    #pragma unroll
    for (int kk=0;kk<4;kk++){
      wv0[kk] = *reinterpret_cast<const f4*>(&W[(size_t)(k0+kk)*128 + c8]);
      wv1[kk] = *reinterpret_cast<const f4*>(&W[(size_t)(k0+kk)*128 + c8 + 4]);
    }
    #pragma unroll
    for (int kk=0;kk<4;kk++)
      #pragma unroll
      for (int i=0;i<8;i++){
        #pragma unroll
        for (int j=0;j<4;j++){
          acc[i][j]   = fmaf(xv[i][kk], wv0[kk][j], acc[i][j]);
          acc[i][j+4] = fmaf(xv[i][kk], wv1[kk][j], acc[i][j+4]);
        }
      }
  }

  const f4 as0 = *reinterpret_cast<const f4*>(&asrc[c8]);
  const f4 as1 = *reinterpret_cast<const f4*>(&asrc[c8+4]);
  const f4 ad0 = *reinterpret_cast<const f4*>(&adst[c8]);
  const f4 ad1 = *reinterpret_cast<const f4*>(&adst[c8+4]);
  const int GT = 16 / H;            // tc-threads per head (H=4 -> 4, H=1 -> 16)
  int hh = tc / GT;

  #pragma unroll
  for (int r=0;r<8;r++){
    int gr = row0 + r8 + r;
    if (gr < n){
      f4 o0 = { acc[r][0], acc[r][1], acc[r][2], acc[r][3] };
      f4 o1 = { acc[r][4], acc[r][5], acc[r][6], acc[r][7] };
      *reinterpret_cast<f4*>(&Hout[(size_t)gr*128 + c8])     = o0;
      *reinterpret_cast<f4*>(&Hout[(size_t)gr*128 + c8 + 4]) = o1;
    }
    float ps = acc[r][0]*as0[0] + acc[r][1]*as0[1] + acc[r][2]*as0[2] + acc[r][3]*as0[3]
             + acc[r][4]*as1[0] + acc[r][5]*as1[1] + acc[r][6]*as1[2] + acc[r][7]*as1[3];
    float pd = acc[r][0]*ad0[0] + acc[r][1]*ad0[1] + acc[r][2]*ad0[2] + acc[r][3]*ad0[3]
             + acc[r][4]*ad1[0] + acc[r][5]*ad1[1] + acc[r][6]*ad1[2] + acc[r][7]*ad1[3];
    #pragma unroll
    for (int m=1;m<GT;m<<=1){ ps += __shfl_xor(ps,m); pd += __shfl_xor(pd,m); }
    if ((tc & (GT-1)) == 0 && gr < n){
      als[(size_t)gr*H + hh] = ps;
      ald[(size_t)gr*H + hh] = pd;
    }
  }
}

// p3: per-block LDS histogram -> slab reservation -> LDS-rank scatter
__device__ __forceinline__ void p3_body(int* lh, int bid,
    const int* __restrict__ ei, int E, int Etot,
    int* __restrict__ bcur, int* __restrict__ tmp)
{
  int* lbase = lh + NBKT;
  int tid = threadIdx.x;
  for (int t = tid; t < NBKT; t += 256) lh[t] = 0;
  __syncthreads();
  int base = bid * P_CHUNK;
  for (int j = 0; j < P_CHUNK; j += 256){
    int i = base + j + tid;
    if (i < Etot){
      int dst = (i < E) ? ei[E + i] : (i - E);
      atomicAdd(&lh[dst >> 7], 1);
    }
  }
  __syncthreads();
  for (int t = tid; t < NBKT; t += 256){
    int v = lh[t];
    lbase[t] = v ? atomicAdd(&bcur[t], v) : 0;
  }
  __syncthreads();
  for (int t = tid; t < NBKT; t += 256) lh[t] = 0;   // reuse as local cursor
  __syncthreads();
  for (int j = 0; j < P_CHUNK; j += 256){
    int i = base + j + tid;
    if (i < Etot){
      int s, d;
      if (i < E){ s = ei[i]; d = ei[E + i]; } else { s = i - E; d = i - E; }
      int b = d >> 7;
      int r = atomicAdd(&lh[b], 1);
      tmp[b*CAP + lbase[b] + r] = s | ((d & 127) << 17);
    }
  }
}

// ---------------- fused: layer-1 gemm blocks + p3 blocks (independent) ----------------
__global__ __launch_bounds__(256) void k_gemm1_p3(
    const float* __restrict__ X, const int* __restrict__ idx,
    const float* __restrict__ W, const float* __restrict__ asrc,
    const float* __restrict__ adst, float* __restrict__ Hout,
    float* __restrict__ als, float* __restrict__ ald, int n, int gb,
    const int* __restrict__ ei, int E, int Etot,
    int* __restrict__ bcur, int* __restrict__ tmp)
{
  __shared__ __align__(16) char smem[128*132*4];   // union: xs (67.6KB) | lh+lbase (8KB)
  if ((int)blockIdx.x < gb){
    gemm_body<4,true>(reinterpret_cast<float(*)[132]>(smem), blockIdx.x,
                      X, idx, W, asrc, adst, Hout, als, ald, n);
  } else {
    p3_body(reinterpret_cast<int*>(smem), blockIdx.x - gb, ei, E, Etot, bcur, tmp);
  }
}

// standalone gemm (layer 2)
template<int H, bool GATHER>
__global__ __launch_bounds__(256) void gemm_al(
    const float* __restrict__ X, const int* __restrict__ idx,
    const float* __restrict__ W, const float* __restrict__ asrc,
    const float* __restrict__ adst, float* __restrict__ Hout,
    float* __restrict__ als, float* __restrict__ ald, int n)
{
  __shared__ float xs[128][132];
  gemm_body<H,GATHER>(xs, blockIdx.x, X, idx, W, asrc, adst, Hout, als, ald, n);
}

// P4: one block per bucket — integrated bbase prefix + per-dst offsets + scatter
__global__ __launch_bounds__(256) void p4local(const int* __restrict__ tmp,
                                               const int* __restrict__ bcnt,
                                               int* __restrict__ off, int* __restrict__ srcs,
                                               int N, int Etot){
  __shared__ int cnt[128];
  __shared__ int offL[128];
  __shared__ int wred[4];
  __shared__ int e0sh;
  int b = blockIdx.x, tid = threadIdx.x, lane = tid & 63, w = tid >> 6;

  int partial = 0;
  for (int t = tid; t < b; t += 256) partial += bcnt[t];
  #pragma unroll
  for (int sh=1; sh<64; sh<<=1) partial += __shfl_xor(partial, sh);
  if (lane == 0) wred[w] = partial;
  if (tid < 128) cnt[tid] = 0;
  __syncthreads();
  if (tid == 0){
    e0sh = wred[0] + wred[1] + wred[2] + wred[3];
    if (b == 0) off[N] = Etot;
  }
  __syncthreads();
  int e0 = e0sh;
  int ne = bcnt[b];
  const int* slab = tmp + (size_t)b*CAP;

  for (int j = tid; j < ne; j += 256)
    atomicAdd(&cnt[(slab[j] >> 17) & 127], 1);
  __syncthreads();
  if (tid < 64){
    int v0 = cnt[2*tid], v1 = cnt[2*tid + 1];
    int p = v0 + v1;
    int x = p;
    #pragma unroll
    for (int d = 1; d < 64; d <<= 1){ int y = __shfl_up(x, d); if (tid >= d) x += y; }
    int excl = x - p;
    offL[2*tid]     = excl;
    offL[2*tid + 1] = excl + v0;
  }
  __syncthreads();
  if (tid < 128){
    int gd = b*128 + tid;
    if (gd < N) off[gd] = e0 + offL[tid];
    cnt[tid] = 0;
  }
  __syncthreads();
  for (int j = tid; j < ne; j += 256){
    int e = slab[j];
    int d = (e >> 17) & 127;
    int r = atomicAdd(&cnt[d], 1);
    srcs[e0 + offL[d] + r] = e & 0x1FFFF;
  }
}

// ---------------- per-dst segment softmax + weighted aggregation ----------------
// r13 form exactly (measured best ~138.5 us). d0/dend: half-range dispatches
// so top-5 profiling reveals the non-aggr dispatches (diagnostic).
template<int H>
__global__ __launch_bounds__(256) void aggr(
    const float* __restrict__ h, const float* __restrict__ als,
    const float* __restrict__ ald, const int* __restrict__ srcs,
    const int* __restrict__ off, const float* __restrict__ bias,
    float* __restrict__ out, int d0, int dend)
{
  __shared__ float s_p[4][64*H];
  __shared__ int   s_s[4][64];
  int tid = threadIdx.x;
  int wid = tid >> 6, lane = tid & 63;
  int d = d0 + blockIdx.x*4 + wid;
  if (d >= dend) return;
  int half = lane >> 5, ch = lane & 31;
  int c4 = ch*4;
  const int hh = (H==1) ? 0 : (ch >> 3);

  int s0 = off[d], s1 = off[d+1];

  float adv[H];
  #pragma unroll
  for (int q=0;q<H;q++) adv[q] = ald[(size_t)d*H + q];

  float m[H], ssum[H];
  #pragma unroll
  for (int q=0;q<H;q++){ m[q] = -INFINITY; ssum[q] = 0.f; }
  float a0=0.f, a1=0.f, a2=0.f, a3=0.f;

  for (int base = s0; base < s1; base += 64){
    int cl = s1 - base; if (cl > 64) cl = 64;

    int sv = 0;
    float e[H];
    if (lane < cl){
      sv = srcs[base + lane];
      #pragma unroll
      for (int q=0;q<H;q++) e[q] = lrelu(als[(size_t)sv*H + q] + adv[q]);
    } else {
      #pragma unroll
      for (int q=0;q<H;q++) e[q] = -INFINITY;
    }

    float cm[H];
    #pragma unroll
    for (int q=0;q<H;q++) cm[q] = e[q];
    #pragma unroll
    for (int sh=1; sh<64; sh<<=1){
      #pragma unroll
      for (int q=0;q<H;q++) cm[q] = fmaxf(cm[q], __shfl_xor(cm[q], sh));
    }

    float p[H], sc[H];
    #pragma unroll
    for (int q=0;q<H;q++){
      float nm = fmaxf(m[q], cm[q]);
      sc[q] = __expf(m[q] - nm);
      ssum[q] *= sc[q];
      m[q] = nm;
      p[q] = __expf(e[q] - nm);
    }
    float schh = sc[0];
    #pragma unroll
    for (int q=1;q<H;q++) schh = (hh==q) ? sc[q] : schh;
    a0 *= schh; a1 *= schh; a2 *= schh; a3 *= schh;

    float cs[H];
    #pragma unroll
    for (int q=0;q<H;q++) cs[q] = p[q];
    #pragma unroll
    for (int sh=1; sh<64; sh<<=1){
      #pragma unroll
      for (int q=0;q<H;q++) cs[q] += __shfl_xor(cs[q], sh);
    }
    #pragma unroll
    for (int q=0;q<H;q++) ssum[q] += cs[q];

    #pragma unroll
    for (int q=0;q<H;q++) s_p[wid][lane*H + q] = p[q];
    s_s[wid][lane] = sv;

    for (int j = half; j < cl; j += 2){
      int s = s_s[wid][j];
      float w = s_p[wid][j*H + hh];
      const float4 hv = *reinterpret_cast<const float4*>(&h[(size_t)s*128 + c4]);
      a0 = fmaf(w, hv.x, a0);
      a1 = fmaf(w, hv.y, a1);
      a2 = fmaf(w, hv.z, a2);
      a3 = fmaf(w, hv.w, a3);
    }
  }

  a0 += __shfl_xor(a0, 32);
  a1 += __shfl_xor(a1, 32);
  a2 += __shfl_xor(a2, 32);
  a3 += __shfl_xor(a3, 32);

  float den = ssum[0];
  #pragma unroll
  for (int q=1;q<H;q++) den = (hh==q) ? ssum[q] : den;
  float inv = 1.f / den;

  if (half == 0){
    const float4 bv = *reinterpret_cast<const float4*>(&bias[c4]);
    float4 o;
    o.x = elu_(a0*inv + bv.x);
    o.y = elu_(a1*inv + bv.y);
    o.z = elu_(a2*inv + bv.z);
    o.w = elu_(a3*inv + bv.w);
    *reinterpret_cast<float4*>(&out[(size_t)d*128 + c4]) = o;
  }
}

// ---------------- global mean pool (batch is sorted) ----------------
__global__ __launch_bounds__(256) void kpool(const float* __restrict__ act,
    const int* __restrict__ batch, int n, float* __restrict__ pool)
{
  __shared__ int sb[2];
  __shared__ float part[128];
  int g = blockIdx.x, tid = threadIdx.x;
  if (tid == 0){
    int lo=0, hi=n;
    while (lo<hi){ int mid=(lo+hi)>>1; if (batch[mid] < g) lo=mid+1; else hi=mid; }
    sb[0]=lo;
    int lo2=lo, hi2=n;
    while (lo2<hi2){ int mid=(lo2+hi2)>>1; if (batch[mid] < g+1) lo2=mid+1; else hi2=mid; }
    sb[1]=lo2;
  }
  __syncthreads();
  int lo=sb[0], hi=sb[1];
  int c = tid & 127, half = tid >> 7;
  float acc = 0.f;
  for (int i=lo+half; i<hi; i+=2) acc += act[(size_t)i*128 + c];
  if (half == 0) part[c] = acc;
  __syncthreads();
  if (half == 1) part[c] += acc;
  __syncthreads();
  if (half == 0){
    float cnt = (float)(hi-lo);
    pool[(size_t)g*128 + c] = part[c] / fmaxf(cnt, 1.f);
  }
}

// ---------------- classifier head ----------------
__global__ __launch_bounds__(64) void kclassify(const float* __restrict__ pool,
    const float* __restrict__ Wc1, const float* __restrict__ bc1,
    const float* __restrict__ Wc2, const float* __restrict__ bc2,
    float* __restrict__ logits)
{
  int g = blockIdx.x, j = threadIdx.x;
  const float* hp = pool + (size_t)g*128;
  float t = bc1[j];
  #pragma unroll 8
  for (int c=0;c<128;c++) t = fmaf(hp[c], Wc1[c*64+j], t);
  t = fmaxf(t, 0.f) * Wc2[j];
  for (int m=1;m<64;m<<=1) t += __shfl_xor(t, m);
  if (j==0) logits[g] = t + bc2[0];
}

extern "C" void kernel_launch(void* const* d_in, const int* in_sizes, int n_in,
                              void* d_out, int out_size, void* d_ws, size_t ws_size,
                              hipStream_t stream)
{
  const int*   x_lex = (const int*)d_in[0];
  const int*   ei    = (const int*)d_in[1];
  const int*   batch = (const int*)d_in[2];
  const float* emb   = (const float*)d_in[3];
  const float* W1    = (const float*)d_in[4];
  const float* a1s   = (const float*)d_in[5];
  const float* a1d   = (const float*)d_in[6];
  const float* b1    = (const float*)d_in[7];
  const float* W2    = (const float*)d_in[8];
  const float* a2s   = (const float*)d_in[9];
  const float* a2d   = (const float*)d_in[10];
  const float* b2    = (const float*)d_in[11];
  const float* Wc1   = (const float*)d_in[12];
  const float* bc1   = (const float*)d_in[13];
  const float* Wc2   = (const float*)d_in[14];
  const float* bc2   = (const float*)d_in[15];

  int N = in_sizes[0];
  int E = in_sizes[1] / 2;
  int Etot = E + N;
  const int G = 256;

  char* p = (char*)d_ws;
  float* hbuf   = (float*)p;          p += (size_t)N*128*4;
  float* act    = (float*)p;          p += (size_t)N*128*4;
  float* als    = (float*)p;          p += (size_t)N*4*4;
  float* ald    = (float*)p;          p += (size_t)N*4*4;
  int*   off    = (int*)p;            p += (size_t)(N+1)*4;
  int*   srcs   = (int*)p;            p += (size_t)Etot*4;
  int*   bcur   = (int*)p;            /* NBKT ints */
  int*   tmp    = (int*)act;          // slabs alias act (p4 reads tmp BEFORE aggr1 writes act)

  // ---- fused: layer-1 gemm + CSR p3 (independent work, one dispatch) ----
  hipMemsetAsync(bcur, 0, NBKT*4, stream);
  int nblk = (Etot + P_CHUNK - 1) / P_CHUNK;
  int nb   = (N + 127) / 128;
  int gb   = (N + 127) / 128;
  k_gemm1_p3<<<gb + nblk, 256, 0, stream>>>(emb, x_lex, W1, a1s, a1d, hbuf, als, ald, N, gb,
                                            ei, E, Etot, bcur, tmp);
  p4local<<<nb, 256, 0, stream>>>(tmp, bcur, off, srcs, N, Etot);

  // ---- layer 1 aggregation (two half-range dispatches: profiling visibility) ----
  int Nh = ((N / 2) + 3) & ~3;
  if (Nh > N) Nh = N;
  aggr<4><<<(Nh+3)/4,256,0,stream>>>(hbuf, als, ald, srcs, off, b1, act, 0, Nh);
  aggr<4><<<(N-Nh+3)/4,256,0,stream>>>(hbuf, als, ald, srcs, off, b1, act, Nh, N);

  // ---- layer 2 ----
  gemm_al<1,false><<<gb,256,0,stream>>>(act, nullptr, W2, a2s, a2d, hbuf, als, ald, N);
  aggr<1><<<(Nh+3)/4,256,0,stream>>>(hbuf, als, ald, srcs, off, b2, act, 0, Nh);
  aggr<1><<<(N-Nh+3)/4,256,0,stream>>>(hbuf, als, ald, srcs, off, b2, act, Nh, N);

  // ---- pool + classifier ----
  float* out = (float*)d_out;
  kpool<<<G,256,0,stream>>>(act, batch, N, out + G);
  kclassify<<<G,64,0,stream>>>(out + G, Wc1, bc1, Wc2, bc2, out);
}

// Round 17
// 473.209 us; speedup vs baseline: 1.0615x; 1.0615x over previous
//
#include <hip/hip_runtime.h>
#include <hip/hip_bf16.h>
#include <math.h>

#define P_CHUNK 8192
#define NBKT 1024   // bucket = dst>>7; used buckets = ceil(N/128)
#define CAP  4096   // slab capacity per bucket (max real bucket ~2350)

typedef float f4 __attribute__((ext_vector_type(4)));

__device__ __forceinline__ float lrelu(float x){ return x < 0.f ? 0.2f*x : x; }
__device__ __forceinline__ float elu_(float x){ return x > 0.f ? x : expm1f(x); }

// ---------------- device bodies ----------------

// GEMM(128x128) + attention-logit epilogue. 64-row tile, 256 thr = 8x32,
// thread owns 8x4 (r13 body; 33.8KB LDS -> 4 blocks/CU). xs natural [row][132];
// per-wave xs reads are 2-addr broadcasts (free). W read from global with
// EXPLICIT one-iteration software prefetch (hides ~200cyc L2 latency under
// the 128-FMA block). ONE barrier.
template<int H, bool GATHER>
__device__ __forceinline__ void gemm_body(float (*xs)[132], int bid,
    const float* __restrict__ X, const int* __restrict__ idx,
    const float* __restrict__ W, const float* __restrict__ asrc,
    const float* __restrict__ adst, float* __restrict__ Hout,
    float* __restrict__ als, float* __restrict__ ald, int n)
{
  int tid = threadIdx.x;
  int tr = tid >> 5, tc = tid & 31;
  int r8 = tr*8, c4 = tc*4;
  int row0 = bid * 64;

  #pragma unroll
  for (int j=0;j<8;j++){
    int e = tid + j*256;
    int r = e >> 5, cq = e & 31;
    int gr = row0 + r;
    f4 v = (f4)(0.f);
    if (gr < n){
      int srow = GATHER ? idx[gr] : gr;
      v = *reinterpret_cast<const f4*>(&X[(size_t)srow*128 + cq*4]);
    }
    *reinterpret_cast<f4*>(&xs[r][cq*4]) = v;
  }
  __syncthreads();

  float acc[8][4];
  #pragma unroll
  for (int r=0;r<8;r++)
    #pragma unroll
    for (int i=0;i<4;i++) acc[r][i] = 0.f;

  // prefetch kq=0 W rows
  f4 wcur[4];
  #pragma unroll
  for (int kk=0;kk<4;kk++) wcur[kk] = *reinterpret_cast<const f4*>(&W[(size_t)kk*128 + c4]);

  for (int kq=0;kq<32;kq++){
    int k0 = kq*4;
    int knxt = (kq < 31) ? (k0 + 4) : k0;     // branchless guard (last iter re-reads, unused)
    f4 wnxt[4];
    #pragma unroll
    for (int kk=0;kk<4;kk++) wnxt[kk] = *reinterpret_cast<const f4*>(&W[(size_t)(knxt+kk)*128 + c4]);

    f4 xv[8];
    #pragma unroll
    for (int i=0;i<8;i++) xv[i] = *reinterpret_cast<const f4*>(&xs[r8+i][k0]);
    #pragma unroll
    for (int kk=0;kk<4;kk++)
      #pragma unroll
      for (int i=0;i<8;i++)
        #pragma unroll
        for (int j=0;j<4;j++)
          acc[i][j] = fmaf(xv[i][kk], wcur[kk][j], acc[i][j]);

    #pragma unroll
    for (int kk=0;kk<4;kk++) wcur[kk] = wnxt[kk];
  }

  const f4 asv = *reinterpret_cast<const f4*>(&asrc[c4]);
  const f4 adv = *reinterpret_cast<const f4*>(&adst[c4]);
  const int GT = 32 / H;            // tc-threads per head (H=4 -> 8, H=1 -> 32)
  int hh = tc / GT;

  #pragma unroll
  for (int r=0;r<8;r++){
    int gr = row0 + r8 + r;
    if (gr < n){
      f4 o = { acc[r][0], acc[r][1], acc[r][2], acc[r][3] };
      *reinterpret_cast<f4*>(&Hout[(size_t)gr*128 + c4]) = o;
    }
    float ps = acc[r][0]*asv[0] + acc[r][1]*asv[1] + acc[r][2]*asv[2] + acc[r][3]*asv[3];
    float pd = acc[r][0]*adv[0] + acc[r][1]*adv[1] + acc[r][2]*adv[2] + acc[r][3]*adv[3];
    #pragma unroll
    for (int m=1;m<GT;m<<=1){ ps += __shfl_xor(ps,m); pd += __shfl_xor(pd,m); }
    if ((tc & (GT-1)) == 0 && gr < n){
      als[(size_t)gr*H + hh] = ps;
      ald[(size_t)gr*H + hh] = pd;
    }
  }
}

// p3: per-block LDS histogram -> slab reservation -> LDS-rank scatter
__device__ __forceinline__ void p3_body(int* lh, int bid,
    const int* __restrict__ ei, int E, int Etot,
    int* __restrict__ bcur, int* __restrict__ tmp)
{
  int* lbase = lh + NBKT;
  int tid = threadIdx.x;
  for (int t = tid; t < NBKT; t += 256) lh[t] = 0;
  __syncthreads();
  int base = bid * P_CHUNK;
  for (int j = 0; j < P_CHUNK; j += 256){
    int i = base + j + tid;
    if (i < Etot){
      int dst = (i < E) ? ei[E + i] : (i - E);
      atomicAdd(&lh[dst >> 7], 1);
    }
  }
  __syncthreads();
  for (int t = tid; t < NBKT; t += 256){
    int v = lh[t];
    lbase[t] = v ? atomicAdd(&bcur[t], v) : 0;
  }
  __syncthreads();
  for (int t = tid; t < NBKT; t += 256) lh[t] = 0;   // reuse as local cursor
  __syncthreads();
  for (int j = 0; j < P_CHUNK; j += 256){
    int i = base + j + tid;
    if (i < Etot){
      int s, d;
      if (i < E){ s = ei[i]; d = ei[E + i]; } else { s = i - E; d = i - E; }
      int b = d >> 7;
      int r = atomicAdd(&lh[b], 1);
      tmp[b*CAP + lbase[b] + r] = s | ((d & 127) << 17);
    }
  }
}

// ---------------- fused: layer-1 gemm blocks + p3 blocks (independent) ----------------
__global__ __launch_bounds__(256) void k_gemm1_p3(
    const float* __restrict__ X, const int* __restrict__ idx,
    const float* __restrict__ W, const float* __restrict__ asrc,
    const float* __restrict__ adst, float* __restrict__ Hout,
    float* __restrict__ als, float* __restrict__ ald, int n, int gb,
    const int* __restrict__ ei, int E, int Etot,
    int* __restrict__ bcur, int* __restrict__ tmp)
{
  __shared__ __align__(16) char smem[64*132*4];   // union: xs (33.8KB) | lh+lbase (8KB)
  if ((int)blockIdx.x < gb){
    gemm_body<4,true>(reinterpret_cast<float(*)[132]>(smem), blockIdx.x,
                      X, idx, W, asrc, adst, Hout, als, ald, n);
  } else {
    p3_body(reinterpret_cast<int*>(smem), blockIdx.x - gb, ei, E, Etot, bcur, tmp);
  }
}

// standalone gemm (layer 2)
template<int H, bool GATHER>
__global__ __launch_bounds__(256) void gemm_al(
    const float* __restrict__ X, const int* __restrict__ idx,
    const float* __restrict__ W, const float* __restrict__ asrc,
    const float* __restrict__ adst, float* __restrict__ Hout,
    float* __restrict__ als, float* __restrict__ ald, int n)
{
  __shared__ float xs[64][132];
  gemm_body<H,GATHER>(xs, blockIdx.x, X, idx, W, asrc, adst, Hout, als, ald, n);
}

// P4: one block per bucket — integrated bbase prefix + per-dst offsets + scatter
__global__ __launch_bounds__(256) void p4local(const int* __restrict__ tmp,
                                               const int* __restrict__ bcnt,
                                               int* __restrict__ off, int* __restrict__ srcs,
                                               int N, int Etot){
  __shared__ int cnt[128];
  __shared__ int offL[128];
  __shared__ int wred[4];
  __shared__ int e0sh;
  int b = blockIdx.x, tid = threadIdx.x, lane = tid & 63, w = tid >> 6;

  int partial = 0;
  for (int t = tid; t < b; t += 256) partial += bcnt[t];
  #pragma unroll
  for (int sh=1; sh<64; sh<<=1) partial += __shfl_xor(partial, sh);
  if (lane == 0) wred[w] = partial;
  if (tid < 128) cnt[tid] = 0;
  __syncthreads();
  if (tid == 0){
    e0sh = wred[0] + wred[1] + wred[2] + wred[3];
    if (b == 0) off[N] = Etot;
  }
  __syncthreads();
  int e0 = e0sh;
  int ne = bcnt[b];
  const int* slab = tmp + (size_t)b*CAP;

  for (int j = tid; j < ne; j += 256)
    atomicAdd(&cnt[(slab[j] >> 17) & 127], 1);
  __syncthreads();
  if (tid < 64){
    int v0 = cnt[2*tid], v1 = cnt[2*tid + 1];
    int p = v0 + v1;
    int x = p;
    #pragma unroll
    for (int d = 1; d < 64; d <<= 1){ int y = __shfl_up(x, d); if (tid >= d) x += y; }
    int excl = x - p;
    offL[2*tid]     = excl;
    offL[2*tid + 1] = excl + v0;
  }
  __syncthreads();
  if (tid < 128){
    int gd = b*128 + tid;
    if (gd < N) off[gd] = e0 + offL[tid];
    cnt[tid] = 0;
  }
  __syncthreads();
  for (int j = tid; j < ne; j += 256){
    int e = slab[j];
    int d = (e >> 17) & 127;
    int r = atomicAdd(&cnt[d], 1);
    srcs[e0 + offL[d] + r] = e & 0x1FFFF;
  }
}

// ---------------- per-dst segment softmax + weighted aggregation ----------------
// r13 form exactly (measured best ~138.5 us — at the L2-miss/L3 gather roofline).
template<int H>
__global__ __launch_bounds__(256) void aggr(
    const float* __restrict__ h, const float* __restrict__ als,
    const float* __restrict__ ald, const int* __restrict__ srcs,
    const int* __restrict__ off, const float* __restrict__ bias,
    float* __restrict__ out, int n)
{
  __shared__ float s_p[4][64*H];
  __shared__ int   s_s[4][64];
  int tid = threadIdx.x;
  int wid = tid >> 6, lane = tid & 63;
  int d = blockIdx.x*4 + wid;
  if (d >= n) return;
  int half = lane >> 5, ch = lane & 31;
  int c4 = ch*4;
  const int hh = (H==1) ? 0 : (ch >> 3);

  int s0 = off[d], s1 = off[d+1];

  float adv[H];
  #pragma unroll
  for (int q=0;q<H;q++) adv[q] = ald[(size_t)d*H + q];

  float m[H], ssum[H];
  #pragma unroll
  for (int q=0;q<H;q++){ m[q] = -INFINITY; ssum[q] = 0.f; }
  float a0=0.f, a1=0.f, a2=0.f, a3=0.f;

  for (int base = s0; base < s1; base += 64){
    int cl = s1 - base; if (cl > 64) cl = 64;

    int sv = 0;
    float e[H];
    if (lane < cl){
      sv = srcs[base + lane];
      #pragma unroll
      for (int q=0;q<H;q++) e[q] = lrelu(als[(size_t)sv*H + q] + adv[q]);
    } else {
      #pragma unroll
      for (int q=0;q<H;q++) e[q] = -INFINITY;
    }

    float cm[H];
    #pragma unroll
    for (int q=0;q<H;q++) cm[q] = e[q];
    #pragma unroll
    for (int sh=1; sh<64; sh<<=1){
      #pragma unroll
      for (int q=0;q<H;q++) cm[q] = fmaxf(cm[q], __shfl_xor(cm[q], sh));
    }

    float p[H], sc[H];
    #pragma unroll
    for (int q=0;q<H;q++){
      float nm = fmaxf(m[q], cm[q]);
      sc[q] = __expf(m[q] - nm);
      ssum[q] *= sc[q];
      m[q] = nm;
      p[q] = __expf(e[q] - nm);
    }
    float schh = sc[0];
    #pragma unroll
    for (int q=1;q<H;q++) schh = (hh==q) ? sc[q] : schh;
    a0 *= schh; a1 *= schh; a2 *= schh; a3 *= schh;

    float cs[H];
    #pragma unroll
    for (int q=0;q<H;q++) cs[q] = p[q];
    #pragma unroll
    for (int sh=1; sh<64; sh<<=1){
      #pragma unroll
      for (int q=0;q<H;q++) cs[q] += __shfl_xor(cs[q], sh);
    }
    #pragma unroll
    for (int q=0;q<H;q++) ssum[q] += cs[q];

    #pragma unroll
    for (int q=0;q<H;q++) s_p[wid][lane*H + q] = p[q];
    s_s[wid][lane] = sv;

    for (int j = half; j < cl; j += 2){
      int s = s_s[wid][j];
      float w = s_p[wid][j*H + hh];
      const float4 hv = *reinterpret_cast<const float4*>(&h[(size_t)s*128 + c4]);
      a0 = fmaf(w, hv.x, a0);
      a1 = fmaf(w, hv.y, a1);
      a2 = fmaf(w, hv.z, a2);
      a3 = fmaf(w, hv.w, a3);
    }
  }

  a0 += __shfl_xor(a0, 32);
  a1 += __shfl_xor(a1, 32);
  a2 += __shfl_xor(a2, 32);
  a3 += __shfl_xor(a3, 32);

  float den = ssum[0];
  #pragma unroll
  for (int q=1;q<H;q++) den = (hh==q) ? ssum[q] : den;
  float inv = 1.f / den;

  if (half == 0){
    const float4 bv = *reinterpret_cast<const float4*>(&bias[c4]);
    float4 o;
    o.x = elu_(a0*inv + bv.x);
    o.y = elu_(a1*inv + bv.y);
    o.z = elu_(a2*inv + bv.z);
    o.w = elu_(a3*inv + bv.w);
    *reinterpret_cast<float4*>(&out[(size_t)d*128 + c4]) = o;
  }
}

// ---------------- fused global mean pool + classifier head ----------------
__global__ __launch_bounds__(256) void kpoolcls(const float* __restrict__ act,
    const int* __restrict__ batch, int n,
    const float* __restrict__ Wc1, const float* __restrict__ bc1,
    const float* __restrict__ Wc2, const float* __restrict__ bc2,
    float* __restrict__ pool, float* __restrict__ logits)
{
  __shared__ int sb[2];
  __shared__ float part[128];
  int g = blockIdx.x, tid = threadIdx.x;
  if (tid == 0){
    int lo=0, hi=n;
    while (lo<hi){ int mid=(lo+hi)>>1; if (batch[mid] < g) lo=mid+1; else hi=mid; }
    sb[0]=lo;
    int lo2=lo, hi2=n;
    while (lo2<hi2){ int mid=(lo2+hi2)>>1; if (batch[mid] < g+1) lo2=mid+1; else hi2=mid; }
    sb[1]=lo2;
  }
  __syncthreads();
  int lo=sb[0], hi=sb[1];
  int c = tid & 127, half = tid >> 7;
  float acc = 0.f;
  for (int i=lo+half; i<hi; i+=2) acc += act[(size_t)i*128 + c];
  if (half == 0) part[c] = acc;
  __syncthreads();
  if (half == 1) part[c] += acc;
  __syncthreads();
  if (half == 0){
    float cnt = (float)(hi-lo);
    float mv = part[c] / fmaxf(cnt, 1.f);
    pool[(size_t)g*128 + c] = mv;
    part[c] = mv;                    // leave mean in LDS for the classifier
  }
  __syncthreads();
  if (tid < 64){
    int j = tid;
    float t = bc1[j];
    #pragma unroll 8
    for (int c2=0;c2<128;c2++) t = fmaf(part[c2], Wc1[c2*64+j], t);
    t = fmaxf(t, 0.f) * Wc2[j];
    #pragma unroll
    for (int m=1;m<64;m<<=1) t += __shfl_xor(t, m);
    if (j==0) logits[g] = t + bc2[0];
  }
}

extern "C" void kernel_launch(void* const* d_in, const int* in_sizes, int n_in,
                              void* d_out, int out_size, void* d_ws, size_t ws_size,
                              hipStream_t stream)
{
  const int*   x_lex = (const int*)d_in[0];
  const int*   ei    = (const int*)d_in[1];
  const int*   batch = (const int*)d_in[2];
  const float* emb   = (const float*)d_in[3];
  const float* W1    = (const float*)d_in[4];
  const float* a1s   = (const float*)d_in[5];
  const float* a1d   = (const float*)d_in[6];
  const float* b1    = (const float*)d_in[7];
  const float* W2    = (const float*)d_in[8];
  const float* a2s   = (const float*)d_in[9];
  const float* a2d   = (const float*)d_in[10];
  const float* b2    = (const float*)d_in[11];
  const float* Wc1   = (const float*)d_in[12];
  const float* bc1   = (const float*)d_in[13];
  const float* Wc2   = (const float*)d_in[14];
  const float* bc2   = (const float*)d_in[15];

  int N = in_sizes[0];
  int E = in_sizes[1] / 2;
  int Etot = E + N;
  const int G = 256;

  char* p = (char*)d_ws;
  float* hbuf   = (float*)p;          p += (size_t)N*128*4;
  float* act    = (float*)p;          p += (size_t)N*128*4;
  float* als    = (float*)p;          p += (size_t)N*4*4;
  float* ald    = (float*)p;          p += (size_t)N*4*4;
  int*   off    = (int*)p;            p += (size_t)(N+1)*4;
  int*   srcs   = (int*)p;            p += (size_t)Etot*4;
  int*   bcur   = (int*)p;            /* NBKT ints */
  int*   tmp    = (int*)act;          // slabs alias act (p4 reads tmp BEFORE aggr1 writes act)

  // ---- fused: layer-1 gemm + CSR p3 (independent work, one dispatch) ----
  hipMemsetAsync(bcur, 0, NBKT*4, stream);
  int nblk = (Etot + P_CHUNK - 1) / P_CHUNK;
  int nb   = (N + 127) / 128;
  int gb   = (N + 63) / 64;
  k_gemm1_p3<<<gb + nblk, 256, 0, stream>>>(emb, x_lex, W1, a1s, a1d, hbuf, als, ald, N, gb,
                                            ei, E, Etot, bcur, tmp);
  p4local<<<nb, 256, 0, stream>>>(tmp, bcur, off, srcs, N, Etot);

  // ---- layer 1 aggregation ----
  aggr<4><<<(N+3)/4,256,0,stream>>>(hbuf, als, ald, srcs, off, b1, act, N);

  // ---- layer 2 ----
  gemm_al<1,false><<<gb,256,0,stream>>>(act, nullptr, W2, a2s, a2d, hbuf, als, ald, N);
  aggr<1><<<(N+3)/4,256,0,stream>>>(hbuf, als, ald, srcs, off, b2, act, N);

  // ---- fused pool + classifier ----
  float* out = (float*)d_out;
  kpoolcls<<<G,256,0,stream>>>(act, batch, N, Wc1, bc1, Wc2, bc2, out + G, out);
}